// Round 3
// baseline (2557.286 us; speedup 1.0000x reference)
//
#include <hip/hip_runtime.h>
#include <stdint.h>

#define NF 65536
#define DIM 512
#define NATTR 256
#define NSTEP 16

typedef __attribute__((ext_vector_type(8))) short s16x8;
typedef __attribute__((ext_vector_type(4))) float f32x4;

__device__ __forceinline__ unsigned short f2bf(float f) {
  union { float f; unsigned u; } v; v.f = f;
  return (unsigned short)((v.u + 0x7fffu + ((v.u >> 16) & 1u)) >> 16);
}
__device__ __forceinline__ float bf2f(unsigned short b) {
  union { unsigned u; float f; } v; v.u = ((unsigned)b) << 16;
  return v.f;
}

// ---------------- prep: column sums of fe (vectorized, 512 blocks) ----------------
__global__ void k_colsum(const float* __restrict__ fe, float* __restrict__ colsum) {
  __shared__ float red[128][4];
  int t = threadIdx.x;
  int cg = t & 127, half = t >> 7;
  int r0 = blockIdx.x * 128 + half * 64;
  float4 s = {0.f, 0.f, 0.f, 0.f};
  for (int r = r0; r < r0 + 64; ++r) {
    float4 v = *(const float4*)&fe[(size_t)r * 512 + cg * 4];
    s.x += v.x; s.y += v.y; s.z += v.z; s.w += v.w;
  }
  if (half) { red[cg][0] = s.x; red[cg][1] = s.y; red[cg][2] = s.z; red[cg][3] = s.w; }
  __syncthreads();
  if (!half) {
    atomicAdd(&colsum[cg * 4 + 0], s.x + red[cg][0]);
    atomicAdd(&colsum[cg * 4 + 1], s.y + red[cg][1]);
    atomicAdd(&colsum[cg * 4 + 2], s.z + red[cg][2]);
    atomicAdd(&colsum[cg * 4 + 3], s.w + red[cg][3]);
  }
}

// ---------------- prep: transpose Wk, Wv (512x512) ----------------
__global__ void k_transpose2(const float* __restrict__ wk, const float* __restrict__ wv,
                             float* __restrict__ wkt, float* __restrict__ wvt) {
  __shared__ float t[64][65];
  const float* src = blockIdx.z ? wv : wk;
  float* dst = blockIdx.z ? wvt : wkt;
  int c0 = blockIdx.x * 64, r0 = blockIdx.y * 64;
  for (int i = 0; i < 16; ++i) {
    int row = i * 4 + (threadIdx.x >> 6), col = threadIdx.x & 63;
    t[row][col] = src[(r0 + row) * 512 + c0 + col];
  }
  __syncthreads();
  for (int i = 0; i < 16; ++i) {
    int row = i * 4 + (threadIdx.x >> 6), col = threadIdx.x & 63;
    dst[(c0 + row) * 512 + r0 + col] = t[col][row];
  }
}

// ---------------- prep: generic C[M][N] = sum_k A[m][k]*B[n][k]  (K=512) ----------------
template <bool BF16OUT>
__global__ void k_abt(const float* __restrict__ A, int lda, int aoff,
                      const float* __restrict__ B, int ldb,
                      void* __restrict__ C, int ldc, int mbase) {
  __shared__ float ta[64][65], tb[64][65];
  int m0 = blockIdx.y * 64, n0 = blockIdx.x * 64;
  int tid = threadIdx.x;
  float acc[4][4] = {};
  for (int k0 = 0; k0 < 512; k0 += 64) {
    __syncthreads();
    for (int i = 0; i < 16; ++i) {
      int e = i * 256 + tid;
      int row = e >> 6, col = e & 63;
      ta[row][col] = A[(m0 + row) * lda + aoff + k0 + col];
      tb[row][col] = B[(n0 + row) * ldb + k0 + col];
    }
    __syncthreads();
    int tr = (tid >> 4) * 4, tc = (tid & 15) * 4;
#pragma unroll 4
    for (int k = 0; k < 64; ++k) {
      float av[4], bv[4];
#pragma unroll
      for (int i = 0; i < 4; ++i) av[i] = ta[tr + i][k];
#pragma unroll
      for (int j = 0; j < 4; ++j) bv[j] = tb[tc + j][k];
#pragma unroll
      for (int i = 0; i < 4; ++i)
#pragma unroll
        for (int j = 0; j < 4; ++j) acc[i][j] += av[i] * bv[j];
    }
  }
  int tr = (tid >> 4) * 4, tc = (tid & 15) * 4;
  for (int i = 0; i < 4; ++i)
    for (int j = 0; j < 4; ++j) {
      int m = mbase + m0 + tr + i, n = n0 + tc + j;
      if (BF16OUT) ((unsigned short*)C)[(size_t)m * ldc + n] = f2bf(acc[i][j]);
      else ((float*)C)[(size_t)m * ldc + n] = acc[i][j];
    }
}

// ---------------- prep: bc[n] = b_ctx @ Wsel[:,n] + bsel[n] ----------------
__global__ void k_bc(const float* __restrict__ wk, const float* __restrict__ bk,
                     const float* __restrict__ wv, const float* __restrict__ bv,
                     const float* __restrict__ bctx, float* __restrict__ bc) {
  int n = blockIdx.x * 256 + threadIdx.x;
  const float* w = n < 512 ? wk : wv;
  const float* b = n < 512 ? bk : bv;
  int col = n & 511;
  float s = b[col];
  for (int t = 0; t < 512; ++t) s += bctx[t] * w[t * 512 + col];
  bc[n] = s;
}

// ---------------- prep: bias2[r] = b_ih[r] + W_ih[r,256:] @ bo ----------------
__global__ void k_bias2(const float* __restrict__ wih, const float* __restrict__ bih,
                        const float* __restrict__ bo, float* __restrict__ bias2) {
  int r = blockIdx.x * 4 + (threadIdx.x >> 6);
  int l = threadIdx.x & 63;
  float s = 0.f;
  for (int j = l; j < 512; j += 64) s += wih[r * 768 + 256 + j] * bo[j];
  for (int mk = 1; mk < 64; mk <<= 1) s += __shfl_xor(s, mk);
  if (l == 0) bias2[r] = s + bih[r];
}

// ---------------- prep: h0 + copy start token ----------------
__global__ void k_h0(const float* __restrict__ wctx, const float* __restrict__ bctx,
                     const float* __restrict__ colsum, const float* __restrict__ stok,
                     float* __restrict__ h, float* __restrict__ pa) {
  if (blockIdx.x == 8) {
    if (threadIdx.x < 256) pa[threadIdx.x] = stok[threadIdx.x];
    return;
  }
  __shared__ float red[4][64];
  int c = blockIdx.x * 64 + (threadIdx.x & 63);
  int chunk = threadIdx.x >> 6;
  float s = 0.f;
  for (int i = chunk * 128; i < chunk * 128 + 128; ++i) s += colsum[i] * wctx[i * 512 + c];
  red[chunk][threadIdx.x & 63] = s;
  __syncthreads();
  if (threadIdx.x < 64) {
    int cc = blockIdx.x * 64 + threadIdx.x;
    float v = red[0][threadIdx.x] + red[1][threadIdx.x] + red[2][threadIdx.x] + red[3][threadIdx.x];
    h[cc] = v * (1.0f / NF) + bctx[cc];
  }
}

// ---------------- prep: qs = (h @ Wq + bq) / 8 ----------------
__global__ void k_q0(const float* __restrict__ h, const float* __restrict__ wq,
                     const float* __restrict__ bq, float* __restrict__ qs) {
  __shared__ float red[4][64];
  int j = blockIdx.x * 64 + (threadIdx.x & 63);
  int chunk = threadIdx.x >> 6;
  float s = 0.f;
  for (int i = chunk * 128; i < chunk * 128 + 128; ++i) s += h[i] * wq[i * 512 + j];
  red[chunk][threadIdx.x & 63] = s;
  __syncthreads();
  if (threadIdx.x < 64) {
    int jj = blockIdx.x * 64 + threadIdx.x;
    float v = red[0][threadIdx.x] + red[1][threadIdx.x] + red[2][threadIdx.x] + red[3][threadIdx.x];
    qs[jj] = (v + bq[jj]) * 0.125f;
  }
}

// ---------------- big dual GEMM: C_kv[65536][1024](bf16) = fe @ Bt^T + bc ----------------
// Swizzle: hw block -> lb=(hw&7)*512+(hw>>3). The 8 blocks sharing an A-panel
// (lb = 8a..8a+7) have hw differing by 8: same XCD AND adjacent dispatch.
__global__ __launch_bounds__(256) void k_gemm(const float* __restrict__ fe,
                                              const unsigned short* __restrict__ bt,
                                              const float* __restrict__ bc,
                                              unsigned short* __restrict__ ckv) {
  __shared__ unsigned short lA[128 * 64];
  __shared__ unsigned short lB[128 * 64];
  int lb = (blockIdx.x & 7) * 512 + (blockIdx.x >> 3);
  int m0 = (lb >> 3) * 128, n0 = (lb & 7) * 128;
  int t = threadIdx.x, l = t & 63, w = t >> 6;
  int wr = (w >> 1) * 64, wc = (w & 1) * 64;
  int lm = l & 15, lkb = (l >> 4) * 16;
  int swz = (lm & 7) << 4;
  f32x4 acc[4][4] = {};
  for (int k0 = 0; k0 < 512; k0 += 64) {
    __syncthreads();
#pragma unroll
    for (int i = 0; i < 8; ++i) {  // stage A: 128x64 fp32 -> bf16 via v_cvt_pk
      int e = i * 1024 + t * 4;
      int row = e >> 6, col = e & 63;
      float4 v = *(const float4*)&fe[(size_t)(m0 + row) * 512 + k0 + col];
      unsigned lo, hi;
      asm("v_cvt_pk_bf16_f32 %0, %1, %2" : "=v"(lo) : "v"(v.x), "v"(v.y));
      asm("v_cvt_pk_bf16_f32 %0, %1, %2" : "=v"(hi) : "v"(v.z), "v"(v.w));
      *(uint2*)((char*)lA + row * 128 + ((col * 2) ^ ((row & 7) << 4))) = make_uint2(lo, hi);
    }
#pragma unroll
    for (int i = 0; i < 4; ++i) {  // stage B: 128x64 bf16
      int e = i * 2048 + t * 8;
      int row = e >> 6, col = e & 63;
      uint4 v = *(const uint4*)&bt[(size_t)(n0 + row) * 512 + k0 + col];
      *(uint4*)((char*)lB + row * 128 + ((col * 2) ^ ((row & 7) << 4))) = v;
    }
    __syncthreads();
#pragma unroll
    for (int ks = 0; ks < 2; ++ks) {
      s16x8 af[4], bf_[4];
      int kb = ks * 64 + lkb;
#pragma unroll
      for (int mi = 0; mi < 4; ++mi)
        af[mi] = *(const s16x8*)((const char*)lA + (wr + mi * 16 + lm) * 128 + (kb ^ swz));
#pragma unroll
      for (int ni = 0; ni < 4; ++ni)
        bf_[ni] = *(const s16x8*)((const char*)lB + (wc + ni * 16 + lm) * 128 + (kb ^ swz));
#pragma unroll
      for (int mi = 0; mi < 4; ++mi)
#pragma unroll
        for (int ni = 0; ni < 4; ++ni)
          acc[mi][ni] = __builtin_amdgcn_mfma_f32_16x16x32_bf16(af[mi], bf_[ni], acc[mi][ni], 0, 0, 0);
    }
  }
#pragma unroll
  for (int mi = 0; mi < 4; ++mi)
#pragma unroll
    for (int ni = 0; ni < 4; ++ni) {
      int n = n0 + wc + ni * 16 + lm;
      float bias = bc[n];
#pragma unroll
      for (int r = 0; r < 4; ++r) {
        int m = m0 + wr + mi * 16 + (l >> 4) * 4 + r;
        ckv[(size_t)m * 1024 + n] = f2bf(acc[mi][ni][r] + bias);
      }
    }
}

// ---------------- step: streaming attention, 16 rows/wave, all loads up front ----------------
// ckv rows: [k(512 bf16) | v(512 bf16)]. Lane l owns cols l*8..l*8+7 (head l>>3).
__global__ __launch_bounds__(256) void k_attn(const unsigned short* __restrict__ ckv,
                                              const float* __restrict__ qs,
                                              float* __restrict__ pm, float* __restrict__ pz,
                                              float* __restrict__ pctx) {
  int t = threadIdx.x, l = t & 63, w = t >> 6;
  int h = l >> 3;
  float qr[8];
  {
    float4 q0 = *(const float4*)&qs[l * 8];
    float4 q1 = *(const float4*)&qs[l * 8 + 4];
    qr[0] = q0.x; qr[1] = q0.y; qr[2] = q0.z; qr[3] = q0.w;
    qr[4] = q1.x; qr[5] = q1.y; qr[6] = q1.z; qr[7] = q1.w;
  }
  int r0 = blockIdx.x * 64 + w * 16;
  const uint4* base = (const uint4*)ckv;  // row r: uint4 index r*128 + l (k), r*128+64+l (v)
  uint4 kk[16], vv[16];
#pragma unroll
  for (int j = 0; j < 16; ++j) {
    kk[j] = base[(size_t)(r0 + j) * 128 + l];
    vv[j] = base[(size_t)(r0 + j) * 128 + 64 + l];
  }
  float dot[16];
#pragma unroll
  for (int j = 0; j < 16; ++j) {
    unsigned ku[4] = {kk[j].x, kk[j].y, kk[j].z, kk[j].w};
    float d = 0.f;
#pragma unroll
    for (int q2 = 0; q2 < 4; ++q2) {
      d += bf2f((unsigned short)(ku[q2] & 0xffffu)) * qr[2 * q2];
      d += bf2f((unsigned short)(ku[q2] >> 16)) * qr[2 * q2 + 1];
    }
    d += __shfl_xor(d, 1);
    d += __shfl_xor(d, 2);
    d += __shfl_xor(d, 4);
    dot[j] = d;
  }
  float m0_ = fmaxf(dot[0], dot[1]);
#pragma unroll
  for (int j = 2; j < 16; ++j) m0_ = fmaxf(m0_, dot[j]);
  float m = m0_, Z = 0.f;
  float wgt[16];
#pragma unroll
  for (int j = 0; j < 16; ++j) { wgt[j] = __expf(dot[j] - m); Z += wgt[j]; }
  float acc[8] = {};
#pragma unroll
  for (int j = 0; j < 16; ++j) {
    unsigned vu[4] = {vv[j].x, vv[j].y, vv[j].z, vv[j].w};
#pragma unroll
    for (int q2 = 0; q2 < 4; ++q2) {
      acc[2 * q2]     += wgt[j] * bf2f((unsigned short)(vu[q2] & 0xffffu));
      acc[2 * q2 + 1] += wgt[j] * bf2f((unsigned short)(vu[q2] >> 16));
    }
  }
  __shared__ float sm[4][8], sz[4][8], sc[4][8][64];
  if ((l & 7) == 0) { sm[w][h] = m; sz[w][h] = Z; }
#pragma unroll
  for (int j = 0; j < 8; ++j) sc[w][h][(l & 7) * 8 + j] = acc[j];
  __syncthreads();
  for (int i = t; i < 512; i += 256) {
    int hh = i >> 6, d = i & 63;
    float M = fmaxf(fmaxf(sm[0][hh], sm[1][hh]), fmaxf(sm[2][hh], sm[3][hh]));
    float c = 0.f;
    for (int ww = 0; ww < 4; ++ww) c += sc[ww][hh][d] * __expf(sm[ww][hh] - M);
    pctx[((size_t)blockIdx.x * 8 + hh) * 64 + d] = c;
    if (d == 0) {
      float zz = 0.f;
      for (int ww = 0; ww < 4; ++ww) zz += sz[ww][hh] * __expf(sm[ww][hh] - M);
      pm[blockIdx.x * 8 + hh] = M;
      pz[blockIdx.x * 8 + hh] = zz;
    }
  }
}

// ---------------- step: combine block partials -> normalized ctx[512] ----------------
__global__ void k_combine(const float* __restrict__ pm, const float* __restrict__ pz,
                          const float* __restrict__ pctx, float* __restrict__ ctx) {
  int h = blockIdx.x, t = threadIdx.x;
  __shared__ float smax[256];
  float lm = -1e30f;
  for (int b = t; b < 1024; b += 256) lm = fmaxf(lm, pm[b * 8 + h]);
  smax[t] = lm;
  __syncthreads();
  for (int s = 128; s > 0; s >>= 1) {
    if (t < s) smax[t] = fmaxf(smax[t], smax[t + s]);
    __syncthreads();
  }
  float M = smax[0];
  int d = t & 63, g = t >> 6;
  float ca = 0.f, za = 0.f;
  for (int b = g; b < 1024; b += 4) {
    float f = __expf(pm[b * 8 + h] - M);
    ca += pctx[((size_t)b * 8 + h) * 64 + d] * f;
    if (d == 0) za += pz[b * 8 + h] * f;
  }
  __shared__ float cs[4][64], zs[4];
  cs[g][d] = ca;
  if (d == 0) zs[g] = za;
  __syncthreads();
  if (t < 64) {
    float c = cs[0][t] + cs[1][t] + cs[2][t] + cs[3][t];
    float Zt = zs[0] + zs[1] + zs[2] + zs[3];
    ctx[h * 64 + t] = c / Zt;
  }
}

// ---------------- step: ih_pre = G@ctx + W_ih[:, :256]@pa + bias2 ; hh = W_hh@h ----------------
__global__ void k_matvec(const float* __restrict__ G, const float* __restrict__ wih,
                         const float* __restrict__ whh, const float* __restrict__ bias2,
                         const float* __restrict__ ctx, const float* __restrict__ pa,
                         const float* __restrict__ h, float* __restrict__ ihp,
                         float* __restrict__ hh) {
  int r = blockIdx.x * 4 + (threadIdx.x >> 6);
  int l = threadIdx.x & 63;
  float s = 0.f;
  if (r < 1536) {
    for (int i = l; i < 512; i += 64) s += G[r * 512 + i] * ctx[i];
    for (int i = l; i < 256; i += 64) s += wih[r * 768 + i] * pa[i];
  } else {
    int r2 = r - 1536;
    for (int i = l; i < 512; i += 64) s += whh[r2 * 512 + i] * h[i];
  }
  for (int mk = 1; mk < 64; mk <<= 1) s += __shfl_xor(s, mk);
  if (l == 0) {
    if (r < 1536) ihp[r] = s + bias2[r];
    else hh[r - 1536] = s;
  }
}

// ---------------- step: GRU gates + heads + next q ----------------
__global__ void k_finish(const float* __restrict__ ihp, const float* __restrict__ hhv,
                         const float* __restrict__ bhn, const float* __restrict__ hold,
                         const float* __restrict__ wq, const float* __restrict__ bq,
                         const float* __restrict__ wattr, const float* __restrict__ battr,
                         const float* __restrict__ wconf, const float* __restrict__ bconf,
                         float* __restrict__ hnew_g, float* __restrict__ panew,
                         float* __restrict__ qs, float* __restrict__ out_a,
                         float* __restrict__ out_c) {
  __shared__ float hn[512];
  __shared__ float red[4][64];
  int t = threadIdx.x;
  for (int c = t; c < 512; c += 256) {
    float ir = ihp[c], iz = ihp[512 + c], inn = ihp[1024 + c];
    float hr = hhv[c], hz = hhv[512 + c], hnn = hhv[1024 + c];
    float r = 1.f / (1.f + __expf(-(ir + hr)));
    float z = 1.f / (1.f + __expf(-(iz + hz)));
    float n = tanhf(inn + r * (hnn + bhn[c]));
    hn[c] = (1.f - z) * n + z * hold[c];
  }
  __syncthreads();
  int b = blockIdx.x;
  if (b < 8) {
    int j = b * 64 + (t & 63), chunk = t >> 6;
    float s = 0.f;
    for (int i = chunk * 128; i < chunk * 128 + 128; ++i) s += hn[i] * wq[i * 512 + j];
    red[chunk][t & 63] = s;
    __syncthreads();
    if (t < 64) {
      int jj = b * 64 + t;
      qs[jj] = (red[0][t] + red[1][t] + red[2][t] + red[3][t] + bq[jj]) * 0.125f;
    }
  } else if (b < 72) {
    int r = (b - 8) * 4 + (t >> 6), l = t & 63;
    float s = 0.f;
    for (int i = l; i < 512; i += 64) s += wattr[r * 512 + i] * hn[i];
    for (int mk = 1; mk < 64; mk <<= 1) s += __shfl_xor(s, mk);
    if (l == 0) {
      float a = s + battr[r];
      out_a[r] = a;
      panew[r] = a;
    }
  } else {
    if (t < 64) {
      float s = 0.f;
      for (int i = t; i < 512; i += 64) s += wconf[i] * hn[i];
      for (int mk = 1; mk < 64; mk <<= 1) s += __shfl_xor(s, mk);
      if (t == 0) out_c[0] = 1.f / (1.f + __expf(-(s + bconf[0])));
    }
    for (int c = t; c < 512; c += 256) hnew_g[c] = hn[c];
  }
}

extern "C" void kernel_launch(void* const* d_in, const int* in_sizes, int n_in,
                              void* d_out, int out_size, void* d_ws, size_t ws_size,
                              hipStream_t stream) {
  (void)in_sizes; (void)n_in; (void)out_size; (void)ws_size;
  const float* fe    = (const float*)d_in[0];
  const float* wctx  = (const float*)d_in[1];
  const float* bctx  = (const float*)d_in[2];
  const float* wq    = (const float*)d_in[3];
  const float* bq    = (const float*)d_in[4];
  const float* wk    = (const float*)d_in[5];
  const float* bk    = (const float*)d_in[6];
  const float* wv    = (const float*)d_in[7];
  const float* bv    = (const float*)d_in[8];
  const float* wo    = (const float*)d_in[9];
  const float* bo    = (const float*)d_in[10];
  const float* wih   = (const float*)d_in[11];
  const float* whh   = (const float*)d_in[12];
  const float* bih   = (const float*)d_in[13];
  const float* bhn   = (const float*)d_in[14];
  const float* stok  = (const float*)d_in[15];
  const float* wattr = (const float*)d_in[16];
  const float* battr = (const float*)d_in[17];
  const float* wconf = (const float*)d_in[18];
  const float* bconf = (const float*)d_in[19];
  float* out = (float*)d_out;

  char* ws = (char*)d_ws;
  unsigned short* ckv   = (unsigned short*)(ws + 0);            // 134217728 B
  unsigned short* btmat = (unsigned short*)(ws + 134217728);    // 1048576 B
  float* wkt    = (float*)(ws + 135266304);
  float* wvt    = (float*)(ws + 136314880);
  float* gmat   = (float*)(ws + 137363456);
  float* bcv    = (float*)(ws + 140509184);
  float* bias2  = (float*)(ws + 140513280);
  float* colsum = (float*)(ws + 140519424);
  float* hbuf   = (float*)(ws + 140521472);
  float* pabuf  = (float*)(ws + 140525568);
  float* qsbuf  = (float*)(ws + 140527616);
  float* ctxbuf = (float*)(ws + 140529664);
  float* ihpb   = (float*)(ws + 140531712);
  float* hhb    = (float*)(ws + 140537856);
  float* pmb    = (float*)(ws + 140544000);
  float* pzb    = (float*)(ws + 140576768);
  float* pctxb  = (float*)(ws + 140609536);

  hipMemsetAsync(colsum, 0, 512 * sizeof(float), stream);
  k_colsum<<<512, 256, 0, stream>>>(fe, colsum);
  k_transpose2<<<dim3(8, 8, 2), 256, 0, stream>>>(wk, wv, wkt, wvt);
  k_abt<false><<<dim3(8, 24), 256, 0, stream>>>(wih, 768, 256, wo, 512, gmat, 512, 0);
  k_abt<true><<<dim3(8, 8), 256, 0, stream>>>(wkt, 512, 0, wctx, 512, btmat, 512, 0);
  k_abt<true><<<dim3(8, 8), 256, 0, stream>>>(wvt, 512, 0, wctx, 512, btmat, 512, 512);
  k_bc<<<4, 256, 0, stream>>>(wk, bk, wv, bv, bctx, bcv);
  k_bias2<<<384, 256, 0, stream>>>(wih, bih, bo, bias2);
  k_h0<<<9, 256, 0, stream>>>(wctx, bctx, colsum, stok, hbuf, pabuf);
  k_q0<<<8, 256, 0, stream>>>(hbuf, wq, bq, qsbuf);
  k_gemm<<<4096, 256, 0, stream>>>(fe, btmat, bcv, ckv);

  for (int s = 0; s < NSTEP; ++s) {
    int cur = s & 1, nxt = cur ^ 1;
    k_attn<<<1024, 256, 0, stream>>>(ckv, qsbuf, pmb, pzb, pctxb);
    k_combine<<<8, 256, 0, stream>>>(pmb, pzb, pctxb, ctxbuf);
    k_matvec<<<768, 256, 0, stream>>>(gmat, wih, whh, bias2, ctxbuf,
                                      pabuf + cur * 256, hbuf + cur * 512, ihpb, hhb);
    k_finish<<<73, 256, 0, stream>>>(ihpb, hhb, bhn, hbuf + cur * 512, wq, bq, wattr, battr,
                                     wconf, bconf, hbuf + nxt * 512, pabuf + nxt * 256,
                                     qsbuf, out + s * 256, out + 4096 + s);
  }
}

// Round 4
// 1762.047 us; speedup vs baseline: 1.4513x; 1.4513x over previous
//
#include <hip/hip_runtime.h>
#include <stdint.h>

#define NF 65536
#define DIM 512
#define NATTR 256
#define NSTEP 16

typedef __attribute__((ext_vector_type(8))) short s16x8;
typedef __attribute__((ext_vector_type(4))) float f32x4;
typedef __attribute__((ext_vector_type(2))) float f32x2;

__device__ __forceinline__ unsigned short f2bf(float f) {
  union { float f; unsigned u; } v; v.f = f;
  return (unsigned short)((v.u + 0x7fffu + ((v.u >> 16) & 1u)) >> 16);
}

#if __has_builtin(__builtin_amdgcn_cvt_pk_f32_fp8) && __has_builtin(__builtin_amdgcn_cvt_pk_fp8_f32)
#define HAVE_FP8_CVT 1
#else
#define HAVE_FP8_CVT 0
#endif

#if !HAVE_FP8_CVT
__device__ __forceinline__ float fp8_to_f32_1(unsigned x) {
  unsigned s = (x & 0x80u) << 24;
  unsigned em = x & 0x7fu;
  union { unsigned u; float f; } v;
  v.u = s | ((em + 960u) << 20);
  float sub = (float)(int)em * 0.001953125f;
  sub = (x & 0x80u) ? -sub : sub;
  return em < 8 ? sub : v.f;
}
__device__ __forceinline__ unsigned f32_to_fp8_1(float f) {
  union { float f; unsigned u; } v; v.f = f;
  unsigned s = (v.u >> 24) & 0x80u;
  unsigned a = v.u & 0x7fffffffu;
  if (a < 0x3c800000u) {
    float m = fabsf(f) * 512.f;
    int mi = (int)(m + 0.5f);
    if (mi > 7) mi = 7;
    return s | (unsigned)mi;
  }
  unsigned r = a + 0x7ffffu + ((a >> 20) & 1u);
  unsigned e4 = (r >> 20) - 960u;
  if (e4 > 0x7eu) e4 = 0x7eu;
  return s | e4;
}
#endif

__device__ __forceinline__ void fp8x4_dec(unsigned w, float* o) {
#if HAVE_FP8_CVT
  f32x2 lo = __builtin_amdgcn_cvt_pk_f32_fp8((int)w, false);
  f32x2 hi = __builtin_amdgcn_cvt_pk_f32_fp8((int)w, true);
  o[0] = lo.x; o[1] = lo.y; o[2] = hi.x; o[3] = hi.y;
#else
  o[0] = fp8_to_f32_1(w & 0xffu);
  o[1] = fp8_to_f32_1((w >> 8) & 0xffu);
  o[2] = fp8_to_f32_1((w >> 16) & 0xffu);
  o[3] = fp8_to_f32_1(w >> 24);
#endif
}
__device__ __forceinline__ unsigned fp8x4_enc(float a, float b, float c, float d) {
#if HAVE_FP8_CVT
  int t0 = __builtin_amdgcn_cvt_pk_fp8_f32(a, b, 0, false);
  return (unsigned)__builtin_amdgcn_cvt_pk_fp8_f32(c, d, t0, true);
#else
  return f32_to_fp8_1(a) | (f32_to_fp8_1(b) << 8) | (f32_to_fp8_1(c) << 16) | (f32_to_fp8_1(d) << 24);
#endif
}

// ---------------- prep: column sums of fe ----------------
__global__ void k_colsum(const float* __restrict__ fe, float* __restrict__ colsum) {
  __shared__ float red[128][4];
  int t = threadIdx.x;
  int cg = t & 127, half = t >> 7;
  int r0 = blockIdx.x * 128 + half * 64;
  float4 s = {0.f, 0.f, 0.f, 0.f};
  for (int r = r0; r < r0 + 64; ++r) {
    float4 v = *(const float4*)&fe[(size_t)r * 512 + cg * 4];
    s.x += v.x; s.y += v.y; s.z += v.z; s.w += v.w;
  }
  if (half) { red[cg][0] = s.x; red[cg][1] = s.y; red[cg][2] = s.z; red[cg][3] = s.w; }
  __syncthreads();
  if (!half) {
    atomicAdd(&colsum[cg * 4 + 0], s.x + red[cg][0]);
    atomicAdd(&colsum[cg * 4 + 1], s.y + red[cg][1]);
    atomicAdd(&colsum[cg * 4 + 2], s.z + red[cg][2]);
    atomicAdd(&colsum[cg * 4 + 3], s.w + red[cg][3]);
  }
}

// ---------------- prep: transpose Wk, Wv ----------------
__global__ void k_transpose2(const float* __restrict__ wk, const float* __restrict__ wv,
                             float* __restrict__ wkt, float* __restrict__ wvt) {
  __shared__ float t[64][65];
  const float* src = blockIdx.z ? wv : wk;
  float* dst = blockIdx.z ? wvt : wkt;
  int c0 = blockIdx.x * 64, r0 = blockIdx.y * 64;
  for (int i = 0; i < 16; ++i) {
    int row = i * 4 + (threadIdx.x >> 6), col = threadIdx.x & 63;
    t[row][col] = src[(r0 + row) * 512 + c0 + col];
  }
  __syncthreads();
  for (int i = 0; i < 16; ++i) {
    int row = i * 4 + (threadIdx.x >> 6), col = threadIdx.x & 63;
    dst[(c0 + row) * 512 + r0 + col] = t[col][row];
  }
}

// ---------------- prep: C[M][N] = scale * sum_k A[m][k]*B[n][k]  (K=512) ----------------
template <bool BF16OUT>
__global__ void k_abt(const float* __restrict__ A, int lda, int aoff,
                      const float* __restrict__ B, int ldb,
                      void* __restrict__ C, int ldc, int mbase, float scale) {
  __shared__ float ta[64][65], tb[64][65];
  int m0 = blockIdx.y * 64, n0 = blockIdx.x * 64;
  int tid = threadIdx.x;
  float acc[4][4] = {};
  for (int k0 = 0; k0 < 512; k0 += 64) {
    __syncthreads();
    for (int i = 0; i < 16; ++i) {
      int e = i * 256 + tid;
      int row = e >> 6, col = e & 63;
      ta[row][col] = A[(m0 + row) * lda + aoff + k0 + col];
      tb[row][col] = B[(n0 + row) * ldb + k0 + col];
    }
    __syncthreads();
    int tr = (tid >> 4) * 4, tc = (tid & 15) * 4;
#pragma unroll 4
    for (int k = 0; k < 64; ++k) {
      float av[4], bv[4];
#pragma unroll
      for (int i = 0; i < 4; ++i) av[i] = ta[tr + i][k];
#pragma unroll
      for (int j = 0; j < 4; ++j) bv[j] = tb[tc + j][k];
#pragma unroll
      for (int i = 0; i < 4; ++i)
#pragma unroll
        for (int j = 0; j < 4; ++j) acc[i][j] += av[i] * bv[j];
    }
  }
  int tr = (tid >> 4) * 4, tc = (tid & 15) * 4;
  for (int i = 0; i < 4; ++i)
    for (int j = 0; j < 4; ++j) {
      int m = mbase + m0 + tr + i, n = n0 + tc + j;
      if (BF16OUT) ((unsigned short*)C)[(size_t)m * ldc + n] = f2bf(acc[i][j] * scale);
      else ((float*)C)[(size_t)m * ldc + n] = acc[i][j] * scale;
    }
}

// ---------------- prep: bc[n] = 16 * (b_ctx @ Wsel[:,n] + bsel[n]) ----------------
__global__ void k_bc(const float* __restrict__ wk, const float* __restrict__ bk,
                     const float* __restrict__ wv, const float* __restrict__ bv,
                     const float* __restrict__ bctx, float* __restrict__ bc) {
  int n = blockIdx.x * 256 + threadIdx.x;
  const float* w = n < 512 ? wk : wv;
  const float* b = n < 512 ? bk : bv;
  int col = n & 511;
  float s = b[col];
  for (int t = 0; t < 512; ++t) s += bctx[t] * w[t * 512 + col];
  bc[n] = s * 16.f;
}

// ---------------- prep: bias2[r] = b_ih[r] + W_ih[r,256:] @ bo ----------------
__global__ void k_bias2(const float* __restrict__ wih, const float* __restrict__ bih,
                        const float* __restrict__ bo, float* __restrict__ bias2) {
  int r = blockIdx.x * 4 + (threadIdx.x >> 6);
  int l = threadIdx.x & 63;
  float s = 0.f;
  for (int j = l; j < 512; j += 64) s += wih[r * 768 + 256 + j] * bo[j];
  for (int mk = 1; mk < 64; mk <<= 1) s += __shfl_xor(s, mk);
  if (l == 0) bias2[r] = s + bih[r];
}

// ---------------- prep: h0 + copy start token ----------------
__global__ void k_h0(const float* __restrict__ wctx, const float* __restrict__ bctx,
                     const float* __restrict__ colsum, const float* __restrict__ stok,
                     float* __restrict__ h, float* __restrict__ pa) {
  if (blockIdx.x == 8) {
    if (threadIdx.x < 256) pa[threadIdx.x] = stok[threadIdx.x];
    return;
  }
  __shared__ float red[4][64];
  int c = blockIdx.x * 64 + (threadIdx.x & 63);
  int chunk = threadIdx.x >> 6;
  float s = 0.f;
  for (int i = chunk * 128; i < chunk * 128 + 128; ++i) s += colsum[i] * wctx[i * 512 + c];
  red[chunk][threadIdx.x & 63] = s;
  __syncthreads();
  if (threadIdx.x < 64) {
    int cc = blockIdx.x * 64 + threadIdx.x;
    float v = red[0][threadIdx.x] + red[1][threadIdx.x] + red[2][threadIdx.x] + red[3][threadIdx.x];
    h[cc] = v * (1.0f / NF) + bctx[cc];
  }
}

// ---------------- prep: qs = (h @ Wq + bq) / (8*16) ----------------
__global__ void k_q0(const float* __restrict__ h, const float* __restrict__ wq,
                     const float* __restrict__ bq, float* __restrict__ qs) {
  __shared__ float red[4][64];
  int j = blockIdx.x * 64 + (threadIdx.x & 63);
  int chunk = threadIdx.x >> 6;
  float s = 0.f;
  for (int i = chunk * 128; i < chunk * 128 + 128; ++i) s += h[i] * wq[i * 512 + j];
  red[chunk][threadIdx.x & 63] = s;
  __syncthreads();
  if (threadIdx.x < 64) {
    int jj = blockIdx.x * 64 + threadIdx.x;
    float v = red[0][threadIdx.x] + red[1][threadIdx.x] + red[2][threadIdx.x] + red[3][threadIdx.x];
    qs[jj] = (v + bq[jj]) * 0.0078125f;
  }
}

// ---------------- big dual GEMM: ckv8[65536][1024](fp8) = 16*(fe @ Bt^T) + bc16 ----------------
// Swapped-operand MFMA: D[row=n][col=m] so each thread owns 4 consecutive n per
// (mi,ni) -> pack 4 fp8 -> swizzled LDS C-tile -> coalesced dword stores.
__global__ __launch_bounds__(256) void k_gemm(const float* __restrict__ fe,
                                              const unsigned short* __restrict__ bt,
                                              const float* __restrict__ bc,
                                              unsigned char* __restrict__ ckv8) {
  __shared__ char smem[32768];
  unsigned short* lA = (unsigned short*)smem;            // 16 KB
  unsigned short* lB = (unsigned short*)(smem + 16384);  // 16 KB
  unsigned* lC = (unsigned*)smem;                        // 16 KB (aliases lA)
  int lb = (blockIdx.x & 7) * 512 + (blockIdx.x >> 3);
  int m0 = (lb >> 3) * 128, n0 = (lb & 7) * 128;
  int t = threadIdx.x, l = t & 63, w = t >> 6;
  int wr = (w >> 1) * 64, wc = (w & 1) * 64;
  int lm = l & 15, lkb = (l >> 4) * 16;
  int swz = (lm & 7) << 4;
  f32x4 acc[4][4] = {};
  for (int k0 = 0; k0 < 512; k0 += 64) {
    __syncthreads();
#pragma unroll
    for (int i = 0; i < 8; ++i) {  // stage A: 128x64 fp32 -> bf16
      int e = i * 1024 + t * 4;
      int row = e >> 6, col = e & 63;
      float4 v = *(const float4*)&fe[(size_t)(m0 + row) * 512 + k0 + col];
      unsigned lo, hi;
      asm("v_cvt_pk_bf16_f32 %0, %1, %2" : "=v"(lo) : "v"(v.x), "v"(v.y));
      asm("v_cvt_pk_bf16_f32 %0, %1, %2" : "=v"(hi) : "v"(v.z), "v"(v.w));
      *(uint2*)((char*)lA + row * 128 + ((col * 2) ^ ((row & 7) << 4))) = make_uint2(lo, hi);
    }
#pragma unroll
    for (int i = 0; i < 4; ++i) {  // stage B: 128x64 bf16
      int e = i * 2048 + t * 8;
      int row = e >> 6, col = e & 63;
      uint4 v = *(const uint4*)&bt[(size_t)(n0 + row) * 512 + k0 + col];
      *(uint4*)((char*)lB + row * 128 + ((col * 2) ^ ((row & 7) << 4))) = v;
    }
    __syncthreads();
#pragma unroll
    for (int ks = 0; ks < 2; ++ks) {
      s16x8 af[4], bf_[4];
      int kb = ks * 64 + lkb;
#pragma unroll
      for (int mi = 0; mi < 4; ++mi)
        af[mi] = *(const s16x8*)((const char*)lA + (wr + mi * 16 + lm) * 128 + (kb ^ swz));
#pragma unroll
      for (int ni = 0; ni < 4; ++ni)
        bf_[ni] = *(const s16x8*)((const char*)lB + (wc + ni * 16 + lm) * 128 + (kb ^ swz));
#pragma unroll
      for (int mi = 0; mi < 4; ++mi)
#pragma unroll
        for (int ni = 0; ni < 4; ++ni)
          acc[mi][ni] = __builtin_amdgcn_mfma_f32_16x16x32_bf16(bf_[ni], af[mi], acc[mi][ni], 0, 0, 0);
    }
  }
  __syncthreads();
  int q4 = l >> 4;
#pragma unroll
  for (int mi = 0; mi < 4; ++mi) {
    int m = wr + mi * 16 + lm;
#pragma unroll
    for (int ni = 0; ni < 4; ++ni) {
      int nb = wc + ni * 16 + q4 * 4;
      float4 b4 = *(const float4*)&bc[n0 + nb];
      float v0 = fmaf(acc[mi][ni][0], 16.f, b4.x);
      float v1 = fmaf(acc[mi][ni][1], 16.f, b4.y);
      float v2 = fmaf(acc[mi][ni][2], 16.f, b4.z);
      float v3 = fmaf(acc[mi][ni][3], 16.f, b4.w);
      lC[m * 32 + ((nb >> 2) ^ (m & 31))] = fp8x4_enc(v0, v1, v2, v3);
    }
  }
  __syncthreads();
#pragma unroll
  for (int i = 0; i < 16; ++i) {
    int lin = i * 256 + t;
    int m = lin >> 5, n4 = lin & 31;
    unsigned pk = lC[m * 32 + (n4 ^ (m & 31))];
    *(unsigned*)(ckv8 + (size_t)(m0 + m) * 1024 + n0 + n4 * 4) = pk;
  }
}

// ---------------- step: streaming attention over fp8 ckv ----------------
// ckv8 row: [k 512 fp8 | v 512 fp8]. Lane l owns cols l*8..l*8+7 (head l>>3).
__global__ __launch_bounds__(256) void k_attn(const unsigned char* __restrict__ ckv8,
                                              const float* __restrict__ qs,
                                              float* __restrict__ pm, float* __restrict__ pz,
                                              float* __restrict__ pctx) {
  int t = threadIdx.x, l = t & 63, w = t >> 6;
  int h = l >> 3;
  float qr[8];
  {
    float4 q0 = *(const float4*)&qs[l * 8];
    float4 q1 = *(const float4*)&qs[l * 8 + 4];
    qr[0] = q0.x; qr[1] = q0.y; qr[2] = q0.z; qr[3] = q0.w;
    qr[4] = q1.x; qr[5] = q1.y; qr[6] = q1.z; qr[7] = q1.w;
  }
  float m = -1e30f, Z = 0.f, acc[8] = {};
  int r0 = blockIdx.x * 128 + w * 32;
#pragma unroll
  for (int c = 0; c < 2; ++c) {
    int rb = r0 + c * 16;
    uint2 kk[16], vv[16];
#pragma unroll
    for (int j = 0; j < 16; ++j) {
      const unsigned char* row = ckv8 + (size_t)(rb + j) * 1024;
      kk[j] = *(const uint2*)(row + l * 8);
      vv[j] = *(const uint2*)(row + 512 + l * 8);
    }
    float dot[16];
#pragma unroll
    for (int j = 0; j < 16; ++j) {
      float kf[8];
      fp8x4_dec(kk[j].x, kf);
      fp8x4_dec(kk[j].y, kf + 4);
      float d = kf[0] * qr[0] + kf[1] * qr[1] + kf[2] * qr[2] + kf[3] * qr[3] +
                kf[4] * qr[4] + kf[5] * qr[5] + kf[6] * qr[6] + kf[7] * qr[7];
      d += __shfl_xor(d, 1);
      d += __shfl_xor(d, 2);
      d += __shfl_xor(d, 4);
      dot[j] = d;
    }
    float cm = dot[0];
#pragma unroll
    for (int j = 1; j < 16; ++j) cm = fmaxf(cm, dot[j]);
    float nm = fmaxf(m, cm);
    float f = __expf(m - nm);
    m = nm; Z *= f;
#pragma unroll
    for (int d2 = 0; d2 < 8; ++d2) acc[d2] *= f;
#pragma unroll
    for (int j = 0; j < 16; ++j) {
      float wgt = __expf(dot[j] - m);
      Z += wgt;
      float vf[8];
      fp8x4_dec(vv[j].x, vf);
      fp8x4_dec(vv[j].y, vf + 4);
#pragma unroll
      for (int d2 = 0; d2 < 8; ++d2) acc[d2] += wgt * vf[d2];
    }
  }
  __shared__ float sm[4][8], sz[4][8], sc[4][8][64];
  if ((l & 7) == 0) { sm[w][h] = m; sz[w][h] = Z; }
#pragma unroll
  for (int j = 0; j < 8; ++j) sc[w][h][(l & 7) * 8 + j] = acc[j];
  __syncthreads();
  for (int i = t; i < 512; i += 256) {
    int hh = i >> 6, d = i & 63;
    float M = fmaxf(fmaxf(sm[0][hh], sm[1][hh]), fmaxf(sm[2][hh], sm[3][hh]));
    float c = 0.f;
    for (int ww = 0; ww < 4; ++ww) c += sc[ww][hh][d] * __expf(sm[ww][hh] - M);
    pctx[((size_t)blockIdx.x * 8 + hh) * 64 + d] = c;
    if (d == 0) {
      float zz = 0.f;
      for (int ww = 0; ww < 4; ++ww) zz += sz[ww][hh] * __expf(sm[ww][hh] - M);
      pm[blockIdx.x * 8 + hh] = M;
      pz[blockIdx.x * 8 + hh] = zz;
    }
  }
}

// ---------------- step: combine 512 block partials -> ctx16[512] ----------------
__global__ void k_combine(const float* __restrict__ pm, const float* __restrict__ pz,
                          const float* __restrict__ pctx, float* __restrict__ ctx) {
  int h = blockIdx.x, t = threadIdx.x;
  __shared__ float smax[256];
  float lm = fmaxf(pm[t * 8 + h], pm[(t + 256) * 8 + h]);
  smax[t] = lm;
  __syncthreads();
  for (int s = 128; s > 0; s >>= 1) {
    if (t < s) smax[t] = fmaxf(smax[t], smax[t + s]);
    __syncthreads();
  }
  float M = smax[0];
  int d = t & 63, g = t >> 6;
  float ca = 0.f, za = 0.f;
#pragma unroll 8
  for (int b = g; b < 512; b += 4) {
    float f = __expf(pm[b * 8 + h] - M);
    ca += pctx[((size_t)b * 8 + h) * 64 + d] * f;
    if (d == 0) za += pz[b * 8 + h] * f;
  }
  __shared__ float cs[4][64], zs[4];
  cs[g][d] = ca;
  if (d == 0) zs[g] = za;
  __syncthreads();
  if (t < 64) {
    float c = cs[0][t] + cs[1][t] + cs[2][t] + cs[3][t];
    float Zt = zs[0] + zs[1] + zs[2] + zs[3];
    ctx[h * 64 + t] = c / Zt;
  }
}

// ---------------- step: ihp = G16@ctx16 + W_ih[:,:256]@pa + bias2 ; hh = W_hh@h ----------------
__global__ void k_matvec(const float* __restrict__ G, const float* __restrict__ wih,
                         const float* __restrict__ whh, const float* __restrict__ bias2,
                         const float* __restrict__ ctx, const float* __restrict__ pa,
                         const float* __restrict__ h, float* __restrict__ ihp,
                         float* __restrict__ hh) {
  int r = blockIdx.x * 4 + (threadIdx.x >> 6);
  int l = threadIdx.x & 63;
  float s = 0.f;
  if (r < 1536) {
    for (int i = l; i < 512; i += 64) s += G[r * 512 + i] * ctx[i];
    for (int i = l; i < 256; i += 64) s += wih[r * 768 + i] * pa[i];
  } else {
    int r2 = r - 1536;
    for (int i = l; i < 512; i += 64) s += whh[r2 * 512 + i] * h[i];
  }
  for (int mk = 1; mk < 64; mk <<= 1) s += __shfl_xor(s, mk);
  if (l == 0) {
    if (r < 1536) ihp[r] = s + bias2[r];
    else hh[r - 1536] = s;
  }
}

// ---------------- step: GRU gates + heads + next q ----------------
__global__ void k_finish(const float* __restrict__ ihp, const float* __restrict__ hhv,
                         const float* __restrict__ bhn, const float* __restrict__ hold,
                         const float* __restrict__ wq, const float* __restrict__ bq,
                         const float* __restrict__ wattr, const float* __restrict__ battr,
                         const float* __restrict__ wconf, const float* __restrict__ bconf,
                         float* __restrict__ hnew_g, float* __restrict__ panew,
                         float* __restrict__ qs, float* __restrict__ out_a,
                         float* __restrict__ out_c) {
  __shared__ float hn[512];
  __shared__ float red[4][64];
  int t = threadIdx.x;
  for (int c = t; c < 512; c += 256) {
    float ir = ihp[c], iz = ihp[512 + c], inn = ihp[1024 + c];
    float hr = hhv[c], hz = hhv[512 + c], hnn = hhv[1024 + c];
    float r = 1.f / (1.f + __expf(-(ir + hr)));
    float z = 1.f / (1.f + __expf(-(iz + hz)));
    float n = tanhf(inn + r * (hnn + bhn[c]));
    hn[c] = (1.f - z) * n + z * hold[c];
  }
  __syncthreads();
  int b = blockIdx.x;
  if (b < 8) {
    int j = b * 64 + (t & 63), chunk = t >> 6;
    float s = 0.f;
    for (int i = chunk * 128; i < chunk * 128 + 128; ++i) s += hn[i] * wq[i * 512 + j];
    red[chunk][t & 63] = s;
    __syncthreads();
    if (t < 64) {
      int jj = b * 64 + t;
      qs[jj] = (red[0][t] + red[1][t] + red[2][t] + red[3][t] + bq[jj]) * 0.0078125f;
    }
  } else if (b < 72) {
    int r = (b - 8) * 4 + (t >> 6), l = t & 63;
    float s = 0.f;
    for (int i = l; i < 512; i += 64) s += wattr[r * 512 + i] * hn[i];
    for (int mk = 1; mk < 64; mk <<= 1) s += __shfl_xor(s, mk);
    if (l == 0) {
      float a = s + battr[r];
      out_a[r] = a;
      panew[r] = a;
    }
  } else {
    if (t < 64) {
      float s = 0.f;
      for (int i = t; i < 512; i += 64) s += wconf[i] * hn[i];
      for (int mk = 1; mk < 64; mk <<= 1) s += __shfl_xor(s, mk);
      if (t == 0) out_c[0] = 1.f / (1.f + __expf(-(s + bconf[0])));
    }
    for (int c = t; c < 512; c += 256) hnew_g[c] = hn[c];
  }
}

extern "C" void kernel_launch(void* const* d_in, const int* in_sizes, int n_in,
                              void* d_out, int out_size, void* d_ws, size_t ws_size,
                              hipStream_t stream) {
  (void)in_sizes; (void)n_in; (void)out_size; (void)ws_size;
  const float* fe    = (const float*)d_in[0];
  const float* wctx  = (const float*)d_in[1];
  const float* bctx  = (const float*)d_in[2];
  const float* wq    = (const float*)d_in[3];
  const float* bq    = (const float*)d_in[4];
  const float* wk    = (const float*)d_in[5];
  const float* bk    = (const float*)d_in[6];
  const float* wv    = (const float*)d_in[7];
  const float* bv    = (const float*)d_in[8];
  const float* wo    = (const float*)d_in[9];
  const float* bo    = (const float*)d_in[10];
  const float* wih   = (const float*)d_in[11];
  const float* whh   = (const float*)d_in[12];
  const float* bih   = (const float*)d_in[13];
  const float* bhn   = (const float*)d_in[14];
  const float* stok  = (const float*)d_in[15];
  const float* wattr = (const float*)d_in[16];
  const float* battr = (const float*)d_in[17];
  const float* wconf = (const float*)d_in[18];
  const float* bconf = (const float*)d_in[19];
  float* out = (float*)d_out;

  char* ws = (char*)d_ws;
  unsigned char* ckv8  = (unsigned char*)(ws + 0);           // 67108864 B
  unsigned short* btmat = (unsigned short*)(ws + 67108864);  // 1048576
  float* wkt    = (float*)(ws + 68157440);                   // 1048576
  float* wvt    = (float*)(ws + 69206016);                   // 1048576
  float* gmat   = (float*)(ws + 70254592);                   // 3145728
  float* bcv    = (float*)(ws + 73400320);                   // 4096
  float* bias2  = (float*)(ws + 73404416);                   // 6144
  float* colsum = (float*)(ws + 73410560);                   // 2048
  float* hbuf   = (float*)(ws + 73412608);                   // 4096
  float* pabuf  = (float*)(ws + 73416704);                   // 2048
  float* qsbuf  = (float*)(ws + 73418752);                   // 2048
  float* ctxbuf = (float*)(ws + 73420800);                   // 2048
  float* ihpb   = (float*)(ws + 73422848);                   // 6144
  float* hhb    = (float*)(ws + 73428992);                   // 6144
  float* pmb    = (float*)(ws + 73435136);                   // 16384
  float* pzb    = (float*)(ws + 73451520);                   // 16384
  float* pctxb  = (float*)(ws + 73467904);                   // 1048576

  k_transpose2<<<dim3(8, 8, 2), 256, 0, stream>>>(wk, wv, wkt, wvt);
  k_abt<false><<<dim3(8, 24), 256, 0, stream>>>(wih, 768, 256, wo, 512, gmat, 512, 0, 0.0625f);
  k_abt<true><<<dim3(8, 8), 256, 0, stream>>>(wkt, 512, 0, wctx, 512, btmat, 512, 0, 1.f);
  k_abt<true><<<dim3(8, 8), 256, 0, stream>>>(wvt, 512, 0, wctx, 512, btmat, 512, 512, 1.f);
  k_bc<<<4, 256, 0, stream>>>(wk, bk, wv, bv, bctx, bcv);
  k_bias2<<<384, 256, 0, stream>>>(wih, bih, bo, bias2);
  k_gemm<<<4096, 256, 0, stream>>>(fe, btmat, bcv, ckv8);
  hipMemsetAsync(colsum, 0, 512 * sizeof(float), stream);
  k_colsum<<<512, 256, 0, stream>>>(fe, colsum);
  k_h0<<<9, 256, 0, stream>>>(wctx, bctx, colsum, stok, hbuf, pabuf);
  k_q0<<<8, 256, 0, stream>>>(hbuf, wq, bq, qsbuf);

  for (int s = 0; s < NSTEP; ++s) {
    int cur = s & 1, nxt = cur ^ 1;
    k_attn<<<512, 256, 0, stream>>>(ckv8, qsbuf, pmb, pzb, pctxb);
    k_combine<<<8, 256, 0, stream>>>(pmb, pzb, pctxb, ctxbuf);
    k_matvec<<<768, 256, 0, stream>>>(gmat, wih, whh, bias2, ctxbuf,
                                      pabuf + cur * 256, hbuf + cur * 512, ihpb, hhb);
    k_finish<<<73, 256, 0, stream>>>(ihpb, hhb, bhn, hbuf + cur * 512, wq, bq, wattr, battr,
                                     wconf, bconf, hbuf + nxt * 512, pabuf + nxt * 256,
                                     qsbuf, out + s * 256, out + 4096 + s);
  }
}